// Round 12
// baseline (21.205 us; speedup 1.0000x reference)
//
#include <hip/hip_runtime.h>
#include <stdint.h>

#define BATCH 2048
#define NPS 8
#define DFEAT 256

// Constant-address-space float: forces s_load (SMEM) codegen for uniform reads.
typedef const float __attribute__((address_space(4))) cfp;
// Address spaces for global_load_lds.
typedef __attribute__((address_space(3))) uint32_t lds_u32;
typedef const __attribute__((address_space(1))) uint32_t glb_u32;

// MAIN KERNEL: byte-identical to round 11 (dur contribution known: 14.64us).
__global__ __launch_bounds__(512) void ppdet_kernel(
    const float* __restrict__ eq,      // (B, 16, 256)
    const float* __restrict__ r_ei,    // (B, 16, 4, 3)
    const float* __restrict__ W,       // (2, 512, 8)
    const float* __restrict__ bias,    // (2, 8)
    const float* __restrict__ env_dim, // (2, 8, 4, 3, 3)
    const float* __restrict__ env_ion, // (2, 4, 8)
    float* __restrict__ out)           // (2, 2048, 8)
{
    __shared__ __align__(16) float X[4 * 64 * 64]; // 64KB, quarter-major
    __shared__ __align__(16) float AB[64 * 16];    // [row][k<8:A+bias, k>=8:Bt]
    __shared__ __align__(16) float envl[512];      // [w][j][k]
    float* part = X;

    const int tid = threadIdx.x;
    const int bid = blockIdx.x;
    const int s  = bid & 1;
    const int b0 = (bid >> 1) * 8;

    const int wq   = __builtin_amdgcn_readfirstlane(tid >> 6);
    const int lane = tid & 63;

    // ---- Env LOADS first (oldest vmcnt entries; keeps gate arithmetic exact)
    const int ew = tid >> 6, ek = (tid >> 3) & 7, ej = tid & 7;
    float4 ra, rb, rc;
    float md[4][9];
    float ei[4];
    {
        const size_t rrow = ((size_t)(b0 + ew) * 16 + s * 8 + ej) * 12;
        const float4* rp = (const float4*)(r_ei + rrow);
        ra = rp[0]; rb = rp[1]; rc = rp[2];
#pragma unroll
        for (int a = 0; a < 4; ++a) {
            const float* Md = env_dim + ((size_t)(s * 8 + ek) * 4 + a) * 9;
            const float4 m0 = *(const float4*)(Md);
            const float4 m1 = *(const float4*)(Md + 4);
            md[a][0] = m0.x; md[a][1] = m0.y; md[a][2] = m0.z; md[a][3] = m0.w;
            md[a][4] = m1.x; md[a][5] = m1.y; md[a][6] = m1.z; md[a][7] = m1.w;
            md[a][8] = Md[8];
            ei[a] = env_ion[(s * 4 + a) * 8 + ek];
        }
    }
    __builtin_amdgcn_sched_barrier(0);

    // ---- Stage issue: 8 DMAs per wave, strict quarter order.
    {
        const float* gw = eq + ((size_t)(b0 + wq) * 16 + s * 8) * DFEAT;
#pragma unroll
        for (int q = 0; q < 4; ++q) {
#pragma unroll
            for (int u = 0; u < 2; ++u) {
                const int r0 = wq * 8 + u * 4;
                const int r  = r0 + (lane >> 4);
                const int c  = (lane & 15) ^ ((r >> 1) & 7);
                const float* src = gw + (size_t)(r & 7) * DFEAT + q * 64 + c * 4;
                lds_u32* dst = (lds_u32*)(uintptr_t)&X[q * 4096 + r0 * 64];
                __builtin_amdgcn_global_load_lds((glb_u32*)src, dst, 16, 0, 0);
            }
            __builtin_amdgcn_sched_barrier(0);
        }
    }

    // ---- Env COMPUTE in the DMA-flight window.
    {
        float rr[12] = {ra.x, ra.y, ra.z, ra.w, rb.x, rb.y, rb.z, rb.w,
                        rc.x, rc.y, rc.z, rc.w};
        float e = 0.f;
#pragma unroll
        for (int a = 0; a < 4; ++a) {
            float r0 = rr[a * 3], r1 = rr[a * 3 + 1], r2 = rr[a * 3 + 2];
            float e0 = r0 * md[a][0] + r1 * md[a][3] + r2 * md[a][6];
            float e1 = r0 * md[a][1] + r1 * md[a][4] + r2 * md[a][7];
            float e2 = r0 * md[a][2] + r1 * md[a][5] + r2 * md[a][8];
            float dist = sqrtf(e0 * e0 + e1 * e1 + e2 * e2);
            e = fmaf(ei[a], __expf(-dist), e);
        }
        envl[ew * 64 + ej * 8 + ek] = e;
    }

    // ---- GEMM: 2 counted-vmcnt phases (BK=128).
    float acc[16];
#pragma unroll
    for (int k = 0; k < 16; ++k) acc[k] = 0.f;

    cfp* wbase = (cfp*)(uintptr_t)(W + s * 4096);
    const int perm = (lane >> 1) & 7;

#pragma unroll
    for (int h = 0; h < 2; ++h) {
        if (h == 0) asm volatile("s_waitcnt vmcnt(4)" ::: "memory");
        else        asm volatile("s_waitcnt vmcnt(0)" ::: "memory");
        __builtin_amdgcn_s_barrier();

#pragma unroll
        for (int qq = 0; qq < 2; ++qq) {
            const int q = h * 2 + qq;
            const float4 xa = *(const float4*)
                &X[q * 4096 + lane * 64 + (((2 * wq)     ^ perm) << 2)];
            const float4 xb = *(const float4*)
                &X[q * 4096 + lane * 64 + (((2 * wq + 1) ^ perm) << 2)];
            cfp* w1 = wbase + (q * 64 + wq * 8) * 8;
            const float xs[8] = {xa.x, xa.y, xa.z, xa.w, xb.x, xb.y, xb.z, xb.w};
#pragma unroll
            for (int i = 0; i < 8; ++i) {
                const float xc = xs[i];
#pragma unroll
                for (int k = 0; k < 8; ++k) {
                    acc[k]     = fmaf(xc, w1[i * 8 + k],        acc[k]);
                    acc[8 + k] = fmaf(xc, w1[2048 + i * 8 + k], acc[8 + k]);
                }
            }
        }
    }

    // ---- Part-store.
    {
        float* pb = part + (wq * 64 + lane) * 16;
        const int sw = (lane >> 1) & 3;
#pragma unroll
        for (int kg = 0; kg < 4; ++kg) {
            int slot = kg ^ sw;
            float4 v = make_float4(acc[kg * 4], acc[kg * 4 + 1],
                                   acc[kg * 4 + 2], acc[kg * 4 + 3]);
            *(float4*)(pb + slot * 4) = v;
        }
    }

    __syncthreads();

    // ---- Reduce 8 f-subset partials -> AB, fold bias into A half.
    if (tid < 256) {
        const int row = tid >> 2, sl = tid & 3;
        const int g = sl ^ ((row >> 1) & 3);
        float4 sum = make_float4(0.f, 0.f, 0.f, 0.f);
#pragma unroll
        for (int q2 = 0; q2 < 8; ++q2) {
            float4 v = *(const float4*)(part + (q2 * 64 + row) * 16 + sl * 4);
            sum.x += v.x; sum.y += v.y; sum.z += v.z; sum.w += v.w;
        }
        if (g < 2) {
            sum.x += bias[s * 8 + g * 4];
            sum.y += bias[s * 8 + g * 4 + 1];
            sum.z += bias[s * 8 + g * 4 + 2];
            sum.w += bias[s * 8 + g * 4 + 3];
        }
        *(float4*)(AB + row * 16 + g * 4) = sum;
    }

    __syncthreads();

    // ---- One 8x8 determinant per thread, in-register LU.
    if (tid < 64) {
        const int w = tid >> 3, i = tid & 7;
        float Arow[8];
#pragma unroll
        for (int k = 0; k < 8; ++k) Arow[k] = AB[(w * 8 + i) * 16 + k];
        float M[8][8];
#pragma unroll
        for (int j = 0; j < 8; ++j) {
#pragma unroll
            for (int k = 0; k < 8; ++k)
                M[j][k] = (Arow[k] + AB[(w * 8 + j) * 16 + 8 + k])
                          * envl[w * 64 + j * 8 + k];
        }
        float det = 1.f;
#pragma unroll
        for (int p = 0; p < 8; ++p) {
            int piv = p;
            float mx = fabsf(M[p][p]);
#pragma unroll
            for (int r2 = p + 1; r2 < 8; ++r2) {
                float v = fabsf(M[r2][p]);
                if (v > mx) { mx = v; piv = r2; }
            }
#pragma unroll
            for (int r2 = p + 1; r2 < 8; ++r2) {
                bool sw = (piv == r2);
#pragma unroll
                for (int c = p; c < 8; ++c) {
                    float a = M[p][c], bb = M[r2][c];
                    M[p][c]  = sw ? bb : a;
                    M[r2][c] = sw ? a : bb;
                }
            }
            det = (piv != p) ? -det : det;
            float d = M[p][p];
            det *= d;
            float inv = (d != 0.f) ? __builtin_amdgcn_rcpf(d) : 0.f;
#pragma unroll
            for (int r2 = p + 1; r2 < 8; ++r2) {
                float fct = M[r2][p] * inv;
#pragma unroll
                for (int c = p + 1; c < 8; ++c) M[r2][c] -= fct * M[p][c];
            }
        }
        out[(size_t)s * (BATCH * NPS) + (size_t)(b0 + w) * NPS + i] = det;
    }
}

// FRONT PROBE: stage + env + gated GEMM + part-store, NO reduce/LU/out.
// All results kept live via an opaque never-taken guard (bias[7] > 1e30)
// feeding a conditional d_ws store -- no DCE, no d_out writes, deterministic.
// front_time = dur_r12 - 14.64 - gap.
__global__ __launch_bounds__(512) void front_probe_kernel(
    const float* __restrict__ eq,
    const float* __restrict__ r_ei,
    const float* __restrict__ W,
    const float* __restrict__ bias,
    const float* __restrict__ env_dim,
    const float* __restrict__ env_ion,
    float* __restrict__ ws)
{
    __shared__ __align__(16) float X[4 * 64 * 64];
    __shared__ __align__(16) float envl[512];
    float* part = X;

    const int tid = threadIdx.x;
    const int bid = blockIdx.x;
    const int s  = bid & 1;
    const int b0 = (bid >> 1) * 8;

    const int wq   = __builtin_amdgcn_readfirstlane(tid >> 6);
    const int lane = tid & 63;

    const int ew = tid >> 6, ek = (tid >> 3) & 7, ej = tid & 7;
    float4 ra, rb, rc;
    float md[4][9];
    float ei[4];
    {
        const size_t rrow = ((size_t)(b0 + ew) * 16 + s * 8 + ej) * 12;
        const float4* rp = (const float4*)(r_ei + rrow);
        ra = rp[0]; rb = rp[1]; rc = rp[2];
#pragma unroll
        for (int a = 0; a < 4; ++a) {
            const float* Md = env_dim + ((size_t)(s * 8 + ek) * 4 + a) * 9;
            const float4 m0 = *(const float4*)(Md);
            const float4 m1 = *(const float4*)(Md + 4);
            md[a][0] = m0.x; md[a][1] = m0.y; md[a][2] = m0.z; md[a][3] = m0.w;
            md[a][4] = m1.x; md[a][5] = m1.y; md[a][6] = m1.z; md[a][7] = m1.w;
            md[a][8] = Md[8];
            ei[a] = env_ion[(s * 4 + a) * 8 + ek];
        }
    }
    __builtin_amdgcn_sched_barrier(0);

    {
        const float* gw = eq + ((size_t)(b0 + wq) * 16 + s * 8) * DFEAT;
#pragma unroll
        for (int q = 0; q < 4; ++q) {
#pragma unroll
            for (int u = 0; u < 2; ++u) {
                const int r0 = wq * 8 + u * 4;
                const int r  = r0 + (lane >> 4);
                const int c  = (lane & 15) ^ ((r >> 1) & 7);
                const float* src = gw + (size_t)(r & 7) * DFEAT + q * 64 + c * 4;
                lds_u32* dst = (lds_u32*)(uintptr_t)&X[q * 4096 + r0 * 64];
                __builtin_amdgcn_global_load_lds((glb_u32*)src, dst, 16, 0, 0);
            }
            __builtin_amdgcn_sched_barrier(0);
        }
    }

    {
        float rr[12] = {ra.x, ra.y, ra.z, ra.w, rb.x, rb.y, rb.z, rb.w,
                        rc.x, rc.y, rc.z, rc.w};
        float e = 0.f;
#pragma unroll
        for (int a = 0; a < 4; ++a) {
            float r0 = rr[a * 3], r1 = rr[a * 3 + 1], r2 = rr[a * 3 + 2];
            float e0 = r0 * md[a][0] + r1 * md[a][3] + r2 * md[a][6];
            float e1 = r0 * md[a][1] + r1 * md[a][4] + r2 * md[a][7];
            float e2 = r0 * md[a][2] + r1 * md[a][5] + r2 * md[a][8];
            float dist = sqrtf(e0 * e0 + e1 * e1 + e2 * e2);
            e = fmaf(ei[a], __expf(-dist), e);
        }
        envl[ew * 64 + ej * 8 + ek] = e;
    }

    float acc[16];
#pragma unroll
    for (int k = 0; k < 16; ++k) acc[k] = 0.f;

    cfp* wbase = (cfp*)(uintptr_t)(W + s * 4096);
    const int perm = (lane >> 1) & 7;

#pragma unroll
    for (int h = 0; h < 2; ++h) {
        if (h == 0) asm volatile("s_waitcnt vmcnt(4)" ::: "memory");
        else        asm volatile("s_waitcnt vmcnt(0)" ::: "memory");
        __builtin_amdgcn_s_barrier();

#pragma unroll
        for (int qq = 0; qq < 2; ++qq) {
            const int q = h * 2 + qq;
            const float4 xa = *(const float4*)
                &X[q * 4096 + lane * 64 + (((2 * wq)     ^ perm) << 2)];
            const float4 xb = *(const float4*)
                &X[q * 4096 + lane * 64 + (((2 * wq + 1) ^ perm) << 2)];
            cfp* w1 = wbase + (q * 64 + wq * 8) * 8;
            const float xs[8] = {xa.x, xa.y, xa.z, xa.w, xb.x, xb.y, xb.z, xb.w};
#pragma unroll
            for (int i = 0; i < 8; ++i) {
                const float xc = xs[i];
#pragma unroll
                for (int k = 0; k < 8; ++k) {
                    acc[k]     = fmaf(xc, w1[i * 8 + k],        acc[k]);
                    acc[8 + k] = fmaf(xc, w1[2048 + i * 8 + k], acc[8 + k]);
                }
            }
        }
    }

    {
        float* pb = part + (wq * 64 + lane) * 16;
        const int sw = (lane >> 1) & 3;
#pragma unroll
        for (int kg = 0; kg < 4; ++kg) {
            int slot = kg ^ sw;
            float4 v = make_float4(acc[kg * 4], acc[kg * 4 + 1],
                                   acc[kg * 4 + 2], acc[kg * 4 + 3]);
            *(float4*)(pb + slot * 4) = v;
        }
    }

    __syncthreads();

    // Opaque keepalive: bias values are ~0.01-scale; condition never true,
    // but the compiler cannot prove it -> part/envl/acc stay live.
    if (bias[7] > 1e30f) {
        ws[tid] = part[tid] + envl[tid & 511] + acc[0];
    }
}

extern "C" void kernel_launch(void* const* d_in, const int* in_sizes, int n_in,
                              void* d_out, int out_size, void* d_ws, size_t ws_size,
                              hipStream_t stream) {
    const float* eq      = (const float*)d_in[0];
    const float* r_ei    = (const float*)d_in[1];
    const float* W       = (const float*)d_in[2];
    const float* bias    = (const float*)d_in[3];
    const float* env_dim = (const float*)d_in[4];
    const float* env_ion = (const float*)d_in[5];
    float* out = (float*)d_out;
    float* ws  = (float*)d_ws;

    ppdet_kernel<<<512, 512, 0, stream>>>(eq, r_ei, W, bias, env_dim, env_ion, out);
    // Diagnostic: front probe; dur delta vs r11 = gap + (stage||env||GEMM).
    front_probe_kernel<<<512, 512, 0, stream>>>(eq, r_ei, W, bias, env_dim,
                                                env_ion, ws);
}

// Round 13
// 18.430 us; speedup vs baseline: 1.1505x; 1.1505x over previous
//
#include <hip/hip_runtime.h>
#include <stdint.h>

#define BATCH 2048
#define NPS 8
#define DFEAT 256

// Constant-address-space float: forces s_load (SMEM) codegen for uniform reads.
typedef const float __attribute__((address_space(4))) cfp;
// Address spaces for global_load_lds.
typedef __attribute__((address_space(3))) uint32_t lds_u32;
typedef const __attribute__((address_space(1))) uint32_t glb_u32;

// 2-TILE PIPELINE: grid 256, one block per 8-walker group; tiles = spin 0,1.
// All 16 DMAs (2 tiles x 4 quarters x 2) issue up front; gates vmcnt(12/8/4/0).
// tile0's part-store+reduce overlaps tile1's staging; the two LU waves (one
// per tile) run concurrently at the end. Mid-pipeline barriers are
// lgkmcnt(0)+s_barrier ONLY (syncthreads would emit vmcnt(0) and drain the
// tile-1 DMAs). env(s0) loads precede the DMAs (oldest vmcnt slots -> gate
// counts exact); env(s1) loads issue after the vmcnt(0) gate (unconstrained).
__global__ __launch_bounds__(512) void ppdet_kernel(
    const float* __restrict__ eq,      // (B, 16, 256)
    const float* __restrict__ r_ei,    // (B, 16, 4, 3)
    const float* __restrict__ W,       // (2, 512, 8)
    const float* __restrict__ bias,    // (2, 8)
    const float* __restrict__ env_dim, // (2, 8, 4, 3, 3)
    const float* __restrict__ env_ion, // (2, 4, 8)
    float* __restrict__ out)           // (2, 2048, 8)
{
    __shared__ __align__(16) float X[2][4 * 64 * 64]; // 128KB, [tile][quarter-major]
    __shared__ __align__(16) float AB[2][64 * 16];    // 8KB
    __shared__ __align__(16) float envl[2][512];      // 4KB
    // part(t) aliases X[t][0..8192) (Q0/Q1 region; no DMA touches it afterwards)

    const int tid = threadIdx.x;
    const int b0 = blockIdx.x * 8;

    const int wq   = __builtin_amdgcn_readfirstlane(tid >> 6); // 0..7, uniform
    const int lane = tid & 63;

    // ---- env(s0) LOADS first (oldest vmcnt entries -> gate counts exact)
    const int ew = tid >> 6, ek = (tid >> 3) & 7, ej = tid & 7;
    float4 ra0, rb0, rc0;
    float md0[4][9];
    float ei0[4];
    {
        const size_t rrow = ((size_t)(b0 + ew) * 16 + 0 * 8 + ej) * 12;
        const float4* rp = (const float4*)(r_ei + rrow);
        ra0 = rp[0]; rb0 = rp[1]; rc0 = rp[2];
#pragma unroll
        for (int a = 0; a < 4; ++a) {
            const float* Md = env_dim + ((size_t)(0 * 8 + ek) * 4 + a) * 9;
            const float4 m0 = *(const float4*)(Md);
            const float4 m1 = *(const float4*)(Md + 4);
            md0[a][0] = m0.x; md0[a][1] = m0.y; md0[a][2] = m0.z; md0[a][3] = m0.w;
            md0[a][4] = m1.x; md0[a][5] = m1.y; md0[a][6] = m1.z; md0[a][7] = m1.w;
            md0[a][8] = Md[8];
            ei0[a] = env_ion[(0 * 4 + a) * 8 + ek];
        }
    }
    __builtin_amdgcn_sched_barrier(0); // env(s0) loads stay ahead of the DMAs

    // ---- Stage issue: 16 DMAs per wave (tile0 Q0..Q3, tile1 Q0..Q3).
#pragma unroll
    for (int t = 0; t < 2; ++t) {
        const float* gw = eq + ((size_t)(b0 + wq) * 16 + t * 8) * DFEAT;
#pragma unroll
        for (int q = 0; q < 4; ++q) {
#pragma unroll
            for (int u = 0; u < 2; ++u) {
                const int r0 = wq * 8 + u * 4;       // wave-uniform row base
                const int r  = r0 + (lane >> 4);     // row this lane feeds
                const int c  = (lane & 15) ^ ((r >> 1) & 7); // src chunk swizzle
                const float* src = gw + (size_t)(r & 7) * DFEAT + q * 64 + c * 4;
                lds_u32* dst = (lds_u32*)(uintptr_t)&X[t][q * 4096 + r0 * 64];
                __builtin_amdgcn_global_load_lds((glb_u32*)src, dst, 16, 0, 0);
            }
            __builtin_amdgcn_sched_barrier(0); // pin issue order per quarter
        }
    }

    // ---- env(s0) COMPUTE in the DMA-flight window.
    {
        float rr[12] = {ra0.x, ra0.y, ra0.z, ra0.w, rb0.x, rb0.y, rb0.z, rb0.w,
                        rc0.x, rc0.y, rc0.z, rc0.w};
        float e = 0.f;
#pragma unroll
        for (int a = 0; a < 4; ++a) {
            float r0 = rr[a * 3], r1 = rr[a * 3 + 1], r2 = rr[a * 3 + 2];
            float e0 = r0 * md0[a][0] + r1 * md0[a][3] + r2 * md0[a][6];
            float e1 = r0 * md0[a][1] + r1 * md0[a][4] + r2 * md0[a][7];
            float e2 = r0 * md0[a][2] + r1 * md0[a][5] + r2 * md0[a][8];
            float dist = sqrtf(e0 * e0 + e1 * e1 + e2 * e2);
            e = fmaf(ei0[a], __expf(-dist), e);
        }
        envl[0][ew * 64 + ej * 8 + ek] = e;
    }

    const int perm = (lane >> 1) & 7;
    float acc[16];
#pragma unroll
    for (int k = 0; k < 16; ++k) acc[k] = 0.f;

    // ================= TILE 0 GEMM =================
    cfp* wbase0 = (cfp*)(uintptr_t)(W);
    asm volatile("s_waitcnt vmcnt(12)" ::: "memory"); // t0 Q0,Q1 landed
    __builtin_amdgcn_s_barrier();
#pragma unroll
    for (int q = 0; q < 2; ++q) {
        const float4 xa = *(const float4*)
            &X[0][q * 4096 + lane * 64 + (((2 * wq)     ^ perm) << 2)];
        const float4 xb = *(const float4*)
            &X[0][q * 4096 + lane * 64 + (((2 * wq + 1) ^ perm) << 2)];
        cfp* w1 = wbase0 + (q * 64 + wq * 8) * 8;
        const float xs[8] = {xa.x, xa.y, xa.z, xa.w, xb.x, xb.y, xb.z, xb.w};
#pragma unroll
        for (int i = 0; i < 8; ++i) {
            const float xc = xs[i];
#pragma unroll
            for (int k = 0; k < 8; ++k) {
                acc[k]     = fmaf(xc, w1[i * 8 + k],        acc[k]);
                acc[8 + k] = fmaf(xc, w1[2048 + i * 8 + k], acc[8 + k]);
            }
        }
    }
    asm volatile("s_waitcnt vmcnt(8)" ::: "memory"); // t0 Q2,Q3 landed
    __builtin_amdgcn_s_barrier();
#pragma unroll
    for (int q = 2; q < 4; ++q) {
        const float4 xa = *(const float4*)
            &X[0][q * 4096 + lane * 64 + (((2 * wq)     ^ perm) << 2)];
        const float4 xb = *(const float4*)
            &X[0][q * 4096 + lane * 64 + (((2 * wq + 1) ^ perm) << 2)];
        cfp* w1 = wbase0 + (q * 64 + wq * 8) * 8;
        const float xs[8] = {xa.x, xa.y, xa.z, xa.w, xb.x, xb.y, xb.z, xb.w};
#pragma unroll
        for (int i = 0; i < 8; ++i) {
            const float xc = xs[i];
#pragma unroll
            for (int k = 0; k < 8; ++k) {
                acc[k]     = fmaf(xc, w1[i * 8 + k],        acc[k]);
                acc[8 + k] = fmaf(xc, w1[2048 + i * 8 + k], acc[8 + k]);
            }
        }
    }

    // ---- part-store0 (X[0] Q0/Q1 region; tile1 staging targets X[1] only)
    {
        float* pb = &X[0][(wq * 64 + lane) * 16];
        const int sw = (lane >> 1) & 3;
#pragma unroll
        for (int kg = 0; kg < 4; ++kg) {
            int slot = kg ^ sw;
            *(float4*)(pb + slot * 4) = make_float4(acc[kg * 4], acc[kg * 4 + 1],
                                                    acc[kg * 4 + 2], acc[kg * 4 + 3]);
        }
    }
    asm volatile("s_waitcnt lgkmcnt(0)" ::: "memory"); // LDS-only barrier:
    __builtin_amdgcn_s_barrier();                      // do NOT drain vmcnt!

    // ---- reduce0 -> AB[0] (overlaps tile1 staging still in flight)
    if (tid < 256) {
        const int row = tid >> 2, sl = tid & 3;
        const int g = sl ^ ((row >> 1) & 3);
        float4 sum = make_float4(0.f, 0.f, 0.f, 0.f);
#pragma unroll
        for (int q2 = 0; q2 < 8; ++q2) {
            float4 v = *(const float4*)&X[0][(q2 * 64 + row) * 16 + sl * 4];
            sum.x += v.x; sum.y += v.y; sum.z += v.z; sum.w += v.w;
        }
        if (g < 2) {
            sum.x += bias[g * 4];
            sum.y += bias[g * 4 + 1];
            sum.z += bias[g * 4 + 2];
            sum.w += bias[g * 4 + 3];
        }
        *(float4*)&AB[0][row * 16 + g * 4] = sum;
    }

    // ================= TILE 1 GEMM =================
#pragma unroll
    for (int k = 0; k < 16; ++k) acc[k] = 0.f;
    cfp* wbase1 = (cfp*)(uintptr_t)(W + 4096);

    asm volatile("s_waitcnt vmcnt(4)" ::: "memory"); // t1 Q0,Q1 landed
    __builtin_amdgcn_s_barrier();
#pragma unroll
    for (int q = 0; q < 2; ++q) {
        const float4 xa = *(const float4*)
            &X[1][q * 4096 + lane * 64 + (((2 * wq)     ^ perm) << 2)];
        const float4 xb = *(const float4*)
            &X[1][q * 4096 + lane * 64 + (((2 * wq + 1) ^ perm) << 2)];
        cfp* w1 = wbase1 + (q * 64 + wq * 8) * 8;
        const float xs[8] = {xa.x, xa.y, xa.z, xa.w, xb.x, xb.y, xb.z, xb.w};
#pragma unroll
        for (int i = 0; i < 8; ++i) {
            const float xc = xs[i];
#pragma unroll
            for (int k = 0; k < 8; ++k) {
                acc[k]     = fmaf(xc, w1[i * 8 + k],        acc[k]);
                acc[8 + k] = fmaf(xc, w1[2048 + i * 8 + k], acc[8 + k]);
            }
        }
    }
    asm volatile("s_waitcnt vmcnt(0)" ::: "memory"); // everything landed
    __builtin_amdgcn_s_barrier();

    // env(s1) loads now (vmcnt fully drained -> no gate-count interaction);
    // their latency hides under the phase-1 fmacs below.
    float4 ra1, rb1, rc1;
    float md1[4][9];
    float ei1[4];
    {
        const size_t rrow = ((size_t)(b0 + ew) * 16 + 1 * 8 + ej) * 12;
        const float4* rp = (const float4*)(r_ei + rrow);
        ra1 = rp[0]; rb1 = rp[1]; rc1 = rp[2];
#pragma unroll
        for (int a = 0; a < 4; ++a) {
            const float* Md = env_dim + ((size_t)(1 * 8 + ek) * 4 + a) * 9;
            const float4 m0 = *(const float4*)(Md);
            const float4 m1 = *(const float4*)(Md + 4);
            md1[a][0] = m0.x; md1[a][1] = m0.y; md1[a][2] = m0.z; md1[a][3] = m0.w;
            md1[a][4] = m1.x; md1[a][5] = m1.y; md1[a][6] = m1.z; md1[a][7] = m1.w;
            md1[a][8] = Md[8];
            ei1[a] = env_ion[(1 * 4 + a) * 8 + ek];
        }
    }

#pragma unroll
    for (int q = 2; q < 4; ++q) {
        const float4 xa = *(const float4*)
            &X[1][q * 4096 + lane * 64 + (((2 * wq)     ^ perm) << 2)];
        const float4 xb = *(const float4*)
            &X[1][q * 4096 + lane * 64 + (((2 * wq + 1) ^ perm) << 2)];
        cfp* w1 = wbase1 + (q * 64 + wq * 8) * 8;
        const float xs[8] = {xa.x, xa.y, xa.z, xa.w, xb.x, xb.y, xb.z, xb.w};
#pragma unroll
        for (int i = 0; i < 8; ++i) {
            const float xc = xs[i];
#pragma unroll
            for (int k = 0; k < 8; ++k) {
                acc[k]     = fmaf(xc, w1[i * 8 + k],        acc[k]);
                acc[8 + k] = fmaf(xc, w1[2048 + i * 8 + k], acc[8 + k]);
            }
        }
    }

    // ---- part-store1 (X[1] Q0/Q1; safe: all waves past the vmcnt(0) barrier
    // finished their Q0/Q1 reads before phase-1 began)
    {
        float* pb = &X[1][(wq * 64 + lane) * 16];
        const int sw = (lane >> 1) & 3;
#pragma unroll
        for (int kg = 0; kg < 4; ++kg) {
            int slot = kg ^ sw;
            *(float4*)(pb + slot * 4) = make_float4(acc[kg * 4], acc[kg * 4 + 1],
                                                    acc[kg * 4 + 2], acc[kg * 4 + 3]);
        }
    }

    // ---- env(s1) compute
    {
        float rr[12] = {ra1.x, ra1.y, ra1.z, ra1.w, rb1.x, rb1.y, rb1.z, rb1.w,
                        rc1.x, rc1.y, rc1.z, rc1.w};
        float e = 0.f;
#pragma unroll
        for (int a = 0; a < 4; ++a) {
            float r0 = rr[a * 3], r1 = rr[a * 3 + 1], r2 = rr[a * 3 + 2];
            float e0 = r0 * md1[a][0] + r1 * md1[a][3] + r2 * md1[a][6];
            float e1 = r0 * md1[a][1] + r1 * md1[a][4] + r2 * md1[a][7];
            float e2 = r0 * md1[a][2] + r1 * md1[a][5] + r2 * md1[a][8];
            float dist = sqrtf(e0 * e0 + e1 * e1 + e2 * e2);
            e = fmaf(ei1[a], __expf(-dist), e);
        }
        envl[1][ew * 64 + ej * 8 + ek] = e;
    }

    asm volatile("s_waitcnt lgkmcnt(0)" ::: "memory");
    __builtin_amdgcn_s_barrier();

    // ---- reduce1 -> AB[1]
    if (tid < 256) {
        const int row = tid >> 2, sl = tid & 3;
        const int g = sl ^ ((row >> 1) & 3);
        float4 sum = make_float4(0.f, 0.f, 0.f, 0.f);
#pragma unroll
        for (int q2 = 0; q2 < 8; ++q2) {
            float4 v = *(const float4*)&X[1][(q2 * 64 + row) * 16 + sl * 4];
            sum.x += v.x; sum.y += v.y; sum.z += v.z; sum.w += v.w;
        }
        if (g < 2) {
            sum.x += bias[8 + g * 4];
            sum.y += bias[8 + g * 4 + 1];
            sum.z += bias[8 + g * 4 + 2];
            sum.w += bias[8 + g * 4 + 3];
        }
        *(float4*)&AB[1][row * 16 + g * 4] = sum;
    }

    asm volatile("s_waitcnt lgkmcnt(0)" ::: "memory");
    __builtin_amdgcn_s_barrier();

    // ---- LU: TWO waves concurrently. wave0 -> tile0's 64 dets, wave1 -> tile1's.
    if (tid < 128) {
        const int t = tid >> 6;
        const int l = tid & 63;
        const int w = l >> 3, i = l & 7;
        const float* ABt = AB[t];
        const float* Et  = envl[t];
        float Arow[8];
#pragma unroll
        for (int k = 0; k < 8; ++k) Arow[k] = ABt[(w * 8 + i) * 16 + k];
        float M[8][8];
#pragma unroll
        for (int j = 0; j < 8; ++j) {
#pragma unroll
            for (int k = 0; k < 8; ++k)
                M[j][k] = (Arow[k] + ABt[(w * 8 + j) * 16 + 8 + k])
                          * Et[w * 64 + j * 8 + k];
        }
        float det = 1.f;
#pragma unroll
        for (int p = 0; p < 8; ++p) {
            int piv = p;
            float mx = fabsf(M[p][p]);
#pragma unroll
            for (int r2 = p + 1; r2 < 8; ++r2) {
                float v = fabsf(M[r2][p]);
                if (v > mx) { mx = v; piv = r2; }
            }
#pragma unroll
            for (int r2 = p + 1; r2 < 8; ++r2) {
                bool sw = (piv == r2);
#pragma unroll
                for (int c = p; c < 8; ++c) {
                    float a = M[p][c], bb = M[r2][c];
                    M[p][c]  = sw ? bb : a;
                    M[r2][c] = sw ? a : bb;
                }
            }
            det = (piv != p) ? -det : det;
            float d = M[p][p];
            det *= d;
            float inv = (d != 0.f) ? __builtin_amdgcn_rcpf(d) : 0.f;
#pragma unroll
            for (int r2 = p + 1; r2 < 8; ++r2) {
                float fct = M[r2][p] * inv;
#pragma unroll
                for (int c = p + 1; c < 8; ++c) M[r2][c] -= fct * M[p][c];
            }
        }
        out[(size_t)t * (BATCH * NPS) + (size_t)(b0 + w) * NPS + i] = det;
    }
}

extern "C" void kernel_launch(void* const* d_in, const int* in_sizes, int n_in,
                              void* d_out, int out_size, void* d_ws, size_t ws_size,
                              hipStream_t stream) {
    const float* eq      = (const float*)d_in[0];
    const float* r_ei    = (const float*)d_in[1];
    const float* W       = (const float*)d_in[2];
    const float* bias    = (const float*)d_in[3];
    const float* env_dim = (const float*)d_in[4];
    const float* env_ion = (const float*)d_in[5];
    float* out = (float*)d_out;

    ppdet_kernel<<<256, 512, 0, stream>>>(eq, r_ei, W, bias, env_dim, env_ion, out);
}

// Round 14
// 15.657 us; speedup vs baseline: 1.3543x; 1.1771x over previous
//
#include <hip/hip_runtime.h>
#include <stdint.h>

#define BATCH 2048
#define NPS 8
#define DFEAT 256

// Constant-address-space float: forces s_load (SMEM) codegen for uniform reads.
typedef const float __attribute__((address_space(4))) cfp;
// Address spaces for global_load_lds.
typedef __attribute__((address_space(3))) uint32_t lds_u32;
typedef const __attribute__((address_space(1))) uint32_t glb_u32;

// Block: 512 threads = 8 waves, 8 walkers x 1 spin (64 rows, 64 dets).
// HYBRID STAGING (vs r11): Q0,Q1 via global_load_lds (coalesced, swizzled
// source, b128-floor LDS reads); Q2,Q3 via per-lane direct float4 loads into
// registers (no LDS round-trip, no barrier, no explicit gate -- per-wave
// compiler vmcnt). Gates: after env is consumed, outstanding = 4 DMA + 4
// direct (FIFO) -> Q0 gate vmcnt(6), Q1 gate vmcnt(4). One post-Q1 barrier
// protects the part-store alias of X. Tail (reduce+LU) = r11 verbatim.
__global__ __launch_bounds__(512) void ppdet_kernel(
    const float* __restrict__ eq,      // (B, 16, 256)
    const float* __restrict__ r_ei,    // (B, 16, 4, 3)
    const float* __restrict__ W,       // (2, 512, 8)
    const float* __restrict__ bias,    // (2, 8)
    const float* __restrict__ env_dim, // (2, 8, 4, 3, 3)
    const float* __restrict__ env_ion, // (2, 4, 8)
    float* __restrict__ out)           // (2, 2048, 8)
{
    __shared__ __align__(16) float X[2 * 64 * 64]; // 32KB: Q0,Q1 only
    __shared__ __align__(16) float AB[64 * 16];    // [row][k<8:A+bias, k>=8:Bt]
    __shared__ __align__(16) float envl[512];      // [w][j][k]
    float* part = X; // 8192 floats = all of X, reused after GEMM reads finish

    const int tid = threadIdx.x;
    const int bid = blockIdx.x;
    const int s  = bid & 1;
    const int b0 = (bid >> 1) * 8;

    const int wq   = __builtin_amdgcn_readfirstlane(tid >> 6); // 0..7, uniform
    const int lane = tid & 63;

    // ---- Env LOADS first (oldest vmcnt entries; consumed before the gates)
    const int ew = tid >> 6, ek = (tid >> 3) & 7, ej = tid & 7;
    float4 ra, rb, rc;
    float md[4][9];
    float ei[4];
    {
        const size_t rrow = ((size_t)(b0 + ew) * 16 + s * 8 + ej) * 12;
        const float4* rp = (const float4*)(r_ei + rrow);
        ra = rp[0]; rb = rp[1]; rc = rp[2];
#pragma unroll
        for (int a = 0; a < 4; ++a) {
            const float* Md = env_dim + ((size_t)(s * 8 + ek) * 4 + a) * 9;
            const float4 m0 = *(const float4*)(Md);
            const float4 m1 = *(const float4*)(Md + 4);
            md[a][0] = m0.x; md[a][1] = m0.y; md[a][2] = m0.z; md[a][3] = m0.w;
            md[a][4] = m1.x; md[a][5] = m1.y; md[a][6] = m1.z; md[a][7] = m1.w;
            md[a][8] = Md[8];
            ei[a] = env_ion[(s * 4 + a) * 8 + ek];
        }
    }
    __builtin_amdgcn_sched_barrier(0); // env loads stay ahead of the DMAs

    // ---- Stage issue: 4 DMAs per wave (Q0, Q1), strict quarter order.
    {
        const float* gw = eq + ((size_t)(b0 + wq) * 16 + s * 8) * DFEAT;
#pragma unroll
        for (int q = 0; q < 2; ++q) {
#pragma unroll
            for (int u = 0; u < 2; ++u) {
                const int r0 = wq * 8 + u * 4;       // wave-uniform row base
                const int r  = r0 + (lane >> 4);     // row this lane feeds
                const int c  = (lane & 15) ^ ((r >> 1) & 7); // src chunk swizzle
                const float* src = gw + (size_t)(r & 7) * DFEAT + q * 64 + c * 4;
                lds_u32* dst = (lds_u32*)(uintptr_t)&X[q * 4096 + r0 * 64];
                __builtin_amdgcn_global_load_lds((glb_u32*)src, dst, 16, 0, 0);
            }
            __builtin_amdgcn_sched_barrier(0); // pin issue order per quarter
        }
    }

    // ---- Direct per-lane loads for Q2,Q3 (issued after the DMAs; newest in
    // the FIFO, consumed via compiler-emitted per-wave vmcnt -- no barrier).
    const float* xr = eq
        + ((size_t)(b0 + (lane >> 3)) * 16 + s * 8 + (lane & 7)) * DFEAT;
    const float4 xg0 = *(const float4*)(xr + 128 + wq * 8);
    const float4 xg1 = *(const float4*)(xr + 128 + wq * 8 + 4);
    const float4 xg2 = *(const float4*)(xr + 192 + wq * 8);
    const float4 xg3 = *(const float4*)(xr + 192 + wq * 8 + 4);
    __builtin_amdgcn_sched_barrier(0); // pin region boundary (gate counts)

    // ---- Env COMPUTE in the DMA/direct-load flight window.
    {
        float rr[12] = {ra.x, ra.y, ra.z, ra.w, rb.x, rb.y, rb.z, rb.w,
                        rc.x, rc.y, rc.z, rc.w};
        float e = 0.f;
#pragma unroll
        for (int a = 0; a < 4; ++a) {
            float r0 = rr[a * 3], r1 = rr[a * 3 + 1], r2 = rr[a * 3 + 2];
            float e0 = r0 * md[a][0] + r1 * md[a][3] + r2 * md[a][6];
            float e1 = r0 * md[a][1] + r1 * md[a][4] + r2 * md[a][7];
            float e2 = r0 * md[a][2] + r1 * md[a][5] + r2 * md[a][8];
            float dist = sqrtf(e0 * e0 + e1 * e1 + e2 * e2);
            e = fmaf(ei[a], __expf(-dist), e);
        }
        envl[ew * 64 + ej * 8 + ek] = e;
    }
    __builtin_amdgcn_sched_barrier(0); // env consumed before gate0

    // ---- GEMM. acc persists across quarters; f-order per k identical to r11.
    float acc[16];
#pragma unroll
    for (int k = 0; k < 16; ++k) acc[k] = 0.f;

    cfp* wbase = (cfp*)(uintptr_t)(W + s * 4096);
    const int perm = (lane >> 1) & 7;

    // Q0/Q1 from LDS, vmcnt-gated (outstanding after env: 4 DMA + 4 direct).
#pragma unroll
    for (int q = 0; q < 2; ++q) {
        if (q == 0) asm volatile("s_waitcnt vmcnt(6)" ::: "memory");
        else        asm volatile("s_waitcnt vmcnt(4)" ::: "memory");
        __builtin_amdgcn_s_barrier();

        const float4 xa = *(const float4*)
            &X[q * 4096 + lane * 64 + (((2 * wq)     ^ perm) << 2)];
        const float4 xb = *(const float4*)
            &X[q * 4096 + lane * 64 + (((2 * wq + 1) ^ perm) << 2)];
        cfp* w1 = wbase + (q * 64 + wq * 8) * 8; // W1 rows; W2 at +2048
        const float xs[8] = {xa.x, xa.y, xa.z, xa.w, xb.x, xb.y, xb.z, xb.w};
#pragma unroll
        for (int i = 0; i < 8; ++i) {
            const float xc = xs[i];
#pragma unroll
            for (int k = 0; k < 8; ++k) {
                acc[k]     = fmaf(xc, w1[i * 8 + k],        acc[k]);
                acc[8 + k] = fmaf(xc, w1[2048 + i * 8 + k], acc[8 + k]);
            }
        }
    }

    // All block-wide X reads are done after this barrier -> part may alias X.
    asm volatile("s_waitcnt lgkmcnt(0)" ::: "memory");
    __builtin_amdgcn_s_barrier();

    // Q2/Q3 from registers (per-wave pace, no barriers).
#pragma unroll
    for (int q = 2; q < 4; ++q) {
        const float4 xa = (q == 2) ? xg0 : xg2;
        const float4 xb = (q == 2) ? xg1 : xg3;
        cfp* w1 = wbase + (q * 64 + wq * 8) * 8;
        const float xs[8] = {xa.x, xa.y, xa.z, xa.w, xb.x, xb.y, xb.z, xb.w};
#pragma unroll
        for (int i = 0; i < 8; ++i) {
            const float xc = xs[i];
#pragma unroll
            for (int k = 0; k < 8; ++k) {
                acc[k]     = fmaf(xc, w1[i * 8 + k],        acc[k]);
                acc[8 + k] = fmaf(xc, w1[2048 + i * 8 + k], acc[8 + k]);
            }
        }
    }

    // ---- Part-store (aliases X; safe after the post-Q1 barrier).
    {
        float* pb = part + (wq * 64 + lane) * 16;
        const int sw = (lane >> 1) & 3;
#pragma unroll
        for (int kg = 0; kg < 4; ++kg) {
            int slot = kg ^ sw;
            float4 v = make_float4(acc[kg * 4], acc[kg * 4 + 1],
                                   acc[kg * 4 + 2], acc[kg * 4 + 3]);
            *(float4*)(pb + slot * 4) = v;
        }
    }

    __syncthreads();

    // ---- Reduce 8 f-subset partials -> AB, fold bias into A half.
    if (tid < 256) {
        const int row = tid >> 2, sl = tid & 3;
        const int g = sl ^ ((row >> 1) & 3); // true k-group held in slot sl
        float4 sum = make_float4(0.f, 0.f, 0.f, 0.f);
#pragma unroll
        for (int q2 = 0; q2 < 8; ++q2) {
            float4 v = *(const float4*)(part + (q2 * 64 + row) * 16 + sl * 4);
            sum.x += v.x; sum.y += v.y; sum.z += v.z; sum.w += v.w;
        }
        if (g < 2) {
            sum.x += bias[s * 8 + g * 4];
            sum.y += bias[s * 8 + g * 4 + 1];
            sum.z += bias[s * 8 + g * 4 + 2];
            sum.w += bias[s * 8 + g * 4 + 3];
        }
        *(float4*)(AB + row * 16 + g * 4) = sum;
    }

    __syncthreads();

    // ---- One 8x8 determinant per thread, in-register LU with partial
    // pivoting; all register indices compile-time constants.
    if (tid < 64) {
        const int w = tid >> 3, i = tid & 7;
        float Arow[8];
#pragma unroll
        for (int k = 0; k < 8; ++k) Arow[k] = AB[(w * 8 + i) * 16 + k];
        float M[8][8];
#pragma unroll
        for (int j = 0; j < 8; ++j) {
#pragma unroll
            for (int k = 0; k < 8; ++k)
                M[j][k] = (Arow[k] + AB[(w * 8 + j) * 16 + 8 + k])
                          * envl[w * 64 + j * 8 + k];
        }
        float det = 1.f;
#pragma unroll
        for (int p = 0; p < 8; ++p) {
            int piv = p;
            float mx = fabsf(M[p][p]);
#pragma unroll
            for (int r2 = p + 1; r2 < 8; ++r2) {
                float v = fabsf(M[r2][p]);
                if (v > mx) { mx = v; piv = r2; }
            }
#pragma unroll
            for (int r2 = p + 1; r2 < 8; ++r2) {
                bool sw = (piv == r2);
#pragma unroll
                for (int c = p; c < 8; ++c) {
                    float a = M[p][c], bb = M[r2][c];
                    M[p][c]  = sw ? bb : a;
                    M[r2][c] = sw ? a : bb;
                }
            }
            det = (piv != p) ? -det : det;
            float d = M[p][p];
            det *= d;
            float inv = (d != 0.f) ? __builtin_amdgcn_rcpf(d) : 0.f;
#pragma unroll
            for (int r2 = p + 1; r2 < 8; ++r2) {
                float fct = M[r2][p] * inv;
#pragma unroll
                for (int c = p + 1; c < 8; ++c) M[r2][c] -= fct * M[p][c];
            }
        }
        out[(size_t)s * (BATCH * NPS) + (size_t)(b0 + w) * NPS + i] = det;
    }
}

extern "C" void kernel_launch(void* const* d_in, const int* in_sizes, int n_in,
                              void* d_out, int out_size, void* d_ws, size_t ws_size,
                              hipStream_t stream) {
    const float* eq      = (const float*)d_in[0];
    const float* r_ei    = (const float*)d_in[1];
    const float* W       = (const float*)d_in[2];
    const float* bias    = (const float*)d_in[3];
    const float* env_dim = (const float*)d_in[4];
    const float* env_ion = (const float*)d_in[5];
    float* out = (float*)d_out;

    ppdet_kernel<<<512, 512, 0, stream>>>(eq, r_ei, W, bias, env_dim, env_ion, out);
}

// Round 15
// 14.850 us; speedup vs baseline: 1.4279x; 1.0544x over previous
//
#include <hip/hip_runtime.h>
#include <stdint.h>

#define BATCH 2048
#define NPS 8
#define DFEAT 256

// Constant-address-space float: forces s_load (SMEM) codegen for uniform reads.
typedef const float __attribute__((address_space(4))) cfp;
// Address spaces for global_load_lds.
typedef __attribute__((address_space(3))) uint32_t lds_u32;
typedef const __attribute__((address_space(1))) uint32_t glb_u32;

// BEST-KNOWN KERNEL (r11, 14.64us): 512 thr = 8 waves, 8 walkers x 1 spin.
// - env loads first (oldest vmcnt slots), env compute in DMA-flight window
// - 8 global_load_lds DMAs (coalesced 1KB, swizzled global source)
// - GEMM: 2 vmcnt-gated phases (BK=128), W via addrspace(4) scalar loads
// - part-store (swizzled slots) -> reduce -> serial in-register LU (rcp)
__global__ __launch_bounds__(512) void ppdet_kernel(
    const float* __restrict__ eq,      // (B, 16, 256)
    const float* __restrict__ r_ei,    // (B, 16, 4, 3)
    const float* __restrict__ W,       // (2, 512, 8)
    const float* __restrict__ bias,    // (2, 8)
    const float* __restrict__ env_dim, // (2, 8, 4, 3, 3)
    const float* __restrict__ env_ion, // (2, 4, 8)
    float* __restrict__ out)           // (2, 2048, 8)
{
    __shared__ __align__(16) float X[4 * 64 * 64]; // 64KB, quarter-major
    __shared__ __align__(16) float AB[64 * 16];    // [row][k<8:A+bias, k>=8:Bt]
    __shared__ __align__(16) float envl[512];      // [w][j][k]
    float* part = X; // 8192 floats = X's Q0+Q1 region, disjoint from Q2/Q3 reads

    const int tid = threadIdx.x;
    const int bid = blockIdx.x;
    const int s  = bid & 1;
    const int b0 = (bid >> 1) * 8;

    const int wq   = __builtin_amdgcn_readfirstlane(tid >> 6); // 0..7, uniform
    const int lane = tid & 63;

    // ---- Env LOADS first (oldest vmcnt entries; keeps gate arithmetic exact)
    const int ew = tid >> 6, ek = (tid >> 3) & 7, ej = tid & 7;
    float4 ra, rb, rc;
    float md[4][9];
    float ei[4];
    {
        const size_t rrow = ((size_t)(b0 + ew) * 16 + s * 8 + ej) * 12;
        const float4* rp = (const float4*)(r_ei + rrow);
        ra = rp[0]; rb = rp[1]; rc = rp[2];
#pragma unroll
        for (int a = 0; a < 4; ++a) {
            const float* Md = env_dim + ((size_t)(s * 8 + ek) * 4 + a) * 9;
            const float4 m0 = *(const float4*)(Md);
            const float4 m1 = *(const float4*)(Md + 4);
            md[a][0] = m0.x; md[a][1] = m0.y; md[a][2] = m0.z; md[a][3] = m0.w;
            md[a][4] = m1.x; md[a][5] = m1.y; md[a][6] = m1.z; md[a][7] = m1.w;
            md[a][8] = Md[8];
            ei[a] = env_ion[(s * 4 + a) * 8 + ek];
        }
    }
    __builtin_amdgcn_sched_barrier(0); // env loads stay ahead of the DMAs

    // ---- Stage issue: 8 DMAs per wave, strict quarter order.
    {
        const float* gw = eq + ((size_t)(b0 + wq) * 16 + s * 8) * DFEAT;
#pragma unroll
        for (int q = 0; q < 4; ++q) {
#pragma unroll
            for (int u = 0; u < 2; ++u) {
                const int r0 = wq * 8 + u * 4;       // wave-uniform row base
                const int r  = r0 + (lane >> 4);     // row this lane feeds
                const int c  = (lane & 15) ^ ((r >> 1) & 7); // src chunk swizzle
                const float* src = gw + (size_t)(r & 7) * DFEAT + q * 64 + c * 4;
                lds_u32* dst = (lds_u32*)(uintptr_t)&X[q * 4096 + r0 * 64];
                __builtin_amdgcn_global_load_lds((glb_u32*)src, dst, 16, 0, 0);
            }
            __builtin_amdgcn_sched_barrier(0); // pin issue order per quarter
        }
    }

    // ---- Env COMPUTE in the DMA-flight window.
    {
        float rr[12] = {ra.x, ra.y, ra.z, ra.w, rb.x, rb.y, rb.z, rb.w,
                        rc.x, rc.y, rc.z, rc.w};
        float e = 0.f;
#pragma unroll
        for (int a = 0; a < 4; ++a) {
            float r0 = rr[a * 3], r1 = rr[a * 3 + 1], r2 = rr[a * 3 + 2];
            float e0 = r0 * md[a][0] + r1 * md[a][3] + r2 * md[a][6];
            float e1 = r0 * md[a][1] + r1 * md[a][4] + r2 * md[a][7];
            float e2 = r0 * md[a][2] + r1 * md[a][5] + r2 * md[a][8];
            float dist = sqrtf(e0 * e0 + e1 * e1 + e2 * e2);
            e = fmaf(ei[a], __expf(-dist), e);
        }
        envl[ew * 64 + ej * 8 + ek] = e;
    }

    // ---- GEMM: 2 counted-vmcnt phases (BK=128). acc persists across phases.
    float acc[16];
#pragma unroll
    for (int k = 0; k < 16; ++k) acc[k] = 0.f;

    cfp* wbase = (cfp*)(uintptr_t)(W + s * 4096);
    const int perm = (lane >> 1) & 7;

#pragma unroll
    for (int h = 0; h < 2; ++h) {
        if (h == 0) asm volatile("s_waitcnt vmcnt(4)" ::: "memory");
        else        asm volatile("s_waitcnt vmcnt(0)" ::: "memory");
        __builtin_amdgcn_s_barrier();

#pragma unroll
        for (int qq = 0; qq < 2; ++qq) {
            const int q = h * 2 + qq;
            // lane = row; un-swizzle on read (b128 at the 8-way floor).
            const float4 xa = *(const float4*)
                &X[q * 4096 + lane * 64 + (((2 * wq)     ^ perm) << 2)];
            const float4 xb = *(const float4*)
                &X[q * 4096 + lane * 64 + (((2 * wq + 1) ^ perm) << 2)];
            cfp* w1 = wbase + (q * 64 + wq * 8) * 8; // W1 rows; W2 at +2048
            const float xs[8] = {xa.x, xa.y, xa.z, xa.w, xb.x, xb.y, xb.z, xb.w};
#pragma unroll
            for (int i = 0; i < 8; ++i) {
                const float xc = xs[i];
#pragma unroll
                for (int k = 0; k < 8; ++k) {
                    acc[k]     = fmaf(xc, w1[i * 8 + k],        acc[k]);
                    acc[8 + k] = fmaf(xc, w1[2048 + i * 8 + k], acc[8 + k]);
                }
            }
        }
    }

    // ---- Part-store (writes X's Q0/Q1 region; phase-1 readers use Q2/Q3).
    {
        float* pb = part + (wq * 64 + lane) * 16;
        const int sw = (lane >> 1) & 3;
#pragma unroll
        for (int kg = 0; kg < 4; ++kg) {
            int slot = kg ^ sw;
            float4 v = make_float4(acc[kg * 4], acc[kg * 4 + 1],
                                   acc[kg * 4 + 2], acc[kg * 4 + 3]);
            *(float4*)(pb + slot * 4) = v;
        }
    }

    __syncthreads();

    // ---- Reduce 8 f-subset partials -> AB, fold bias into A half.
    if (tid < 256) {
        const int row = tid >> 2, sl = tid & 3;
        const int g = sl ^ ((row >> 1) & 3); // true k-group held in slot sl
        float4 sum = make_float4(0.f, 0.f, 0.f, 0.f);
#pragma unroll
        for (int q2 = 0; q2 < 8; ++q2) {
            float4 v = *(const float4*)(part + (q2 * 64 + row) * 16 + sl * 4);
            sum.x += v.x; sum.y += v.y; sum.z += v.z; sum.w += v.w;
        }
        if (g < 2) {
            sum.x += bias[s * 8 + g * 4];
            sum.y += bias[s * 8 + g * 4 + 1];
            sum.z += bias[s * 8 + g * 4 + 2];
            sum.w += bias[s * 8 + g * 4 + 3];
        }
        *(float4*)(AB + row * 16 + g * 4) = sum;
    }

    __syncthreads();

    // ---- One 8x8 determinant per thread, in-register LU with partial
    // pivoting; all register indices compile-time constants. rcp for the
    // elimination factor (validated r2/r10: absmax ~1e-6, threshold 6.6e-4).
    if (tid < 64) {
        const int w = tid >> 3, i = tid & 7;
        float Arow[8];
#pragma unroll
        for (int k = 0; k < 8; ++k) Arow[k] = AB[(w * 8 + i) * 16 + k];
        float M[8][8];
#pragma unroll
        for (int j = 0; j < 8; ++j) {
#pragma unroll
            for (int k = 0; k < 8; ++k)
                M[j][k] = (Arow[k] + AB[(w * 8 + j) * 16 + 8 + k])
                          * envl[w * 64 + j * 8 + k];
        }
        float det = 1.f;
#pragma unroll
        for (int p = 0; p < 8; ++p) {
            int piv = p;
            float mx = fabsf(M[p][p]);
#pragma unroll
            for (int r2 = p + 1; r2 < 8; ++r2) {
                float v = fabsf(M[r2][p]);
                if (v > mx) { mx = v; piv = r2; }
            }
#pragma unroll
            for (int r2 = p + 1; r2 < 8; ++r2) {
                bool sw = (piv == r2);
#pragma unroll
                for (int c = p; c < 8; ++c) {
                    float a = M[p][c], bb = M[r2][c];
                    M[p][c]  = sw ? bb : a;
                    M[r2][c] = sw ? a : bb;
                }
            }
            det = (piv != p) ? -det : det;
            float d = M[p][p];
            det *= d;
            float inv = (d != 0.f) ? __builtin_amdgcn_rcpf(d) : 0.f;
#pragma unroll
            for (int r2 = p + 1; r2 < 8; ++r2) {
                float fct = M[r2][p] * inv;
#pragma unroll
                for (int c = p + 1; c < 8; ++c) M[r2][c] -= fct * M[p][c];
            }
        }
        out[(size_t)s * (BATCH * NPS) + (size_t)(b0 + w) * NPS + i] = det;
    }
}

extern "C" void kernel_launch(void* const* d_in, const int* in_sizes, int n_in,
                              void* d_out, int out_size, void* d_ws, size_t ws_size,
                              hipStream_t stream) {
    const float* eq      = (const float*)d_in[0];
    const float* r_ei    = (const float*)d_in[1];
    const float* W       = (const float*)d_in[2];
    const float* bias    = (const float*)d_in[3];
    const float* env_dim = (const float*)d_in[4];
    const float* env_ion = (const float*)d_in[5];
    float* out = (float*)d_out;

    ppdet_kernel<<<512, 512, 0, stream>>>(eq, r_ei, W, bias, env_dim, env_ion, out);
}